// Round 5
// baseline (243.694 us; speedup 1.0000x reference)
//
#include <hip/hip_runtime.h>
#include <stdint.h>

// Problem constants: B=2, Q=1024, N=4096, C=768, H=12, D=64, REL=32
// Inputs/outputs fp32 (established R1/R2).
typedef unsigned short ushort_t;
typedef __bf16 bf16x8 __attribute__((ext_vector_type(8)));
typedef float f32x4 __attribute__((ext_vector_type(4)));
typedef unsigned short us4 __attribute__((ext_vector_type(4)));

#define LOG2E 1.4426950408889634f
#define NEG8L (-11.541560327111707f)   // -8*log2(e)
#define QSCALE 0.18033688011110974f    // 0.125*log2(e)

__device__ __forceinline__ ushort_t f2b(float f) {
    unsigned u = __float_as_uint(f);
    unsigned r = (u + 0x7fffu + ((u >> 16) & 1u)) >> 16;
    return (ushort_t)r;
}
__device__ __forceinline__ void gld16(const void* g, void* l) {
    __builtin_amdgcn_global_load_lds(
        (__attribute__((address_space(1))) void*)g,
        (__attribute__((address_space(3))) void*)l,
        16, 0, 0);
}

// ------------------------------------------------------------ fused prep
// [0,1536): query f32->bf16  [1536,7680): key_value f32->bf16
// [7680,9984): 4x weight transpose  [9984,11520): bias q-lerp (x LOG2E)
// [11520,11536): n-lerp weight table
__global__ __launch_bounds__(256) void prep(
        const float* __restrict__ query, const float* __restrict__ keyv,
        const float* __restrict__ Wq, const float* __restrict__ Wk,
        const float* __restrict__ Wv, const float* __restrict__ Wo,
        const float* __restrict__ rel,
        ushort_t* __restrict__ qc, ushort_t* __restrict__ kvc,
        ushort_t* __restrict__ wtq, ushort_t* __restrict__ wtk,
        ushort_t* __restrict__ wtv, ushort_t* __restrict__ wto,
        ushort_t* __restrict__ b1b, ushort_t* __restrict__ wtab) {
    __shared__ ushort_t tsh[32][33];
    const int bid = blockIdx.x, tid = threadIdx.x;
    if (bid < 7680) {
        const float* src = (bid < 1536) ? query : keyv;
        ushort_t* dst = (bid < 1536) ? qc : kvc;
        int i = ((bid < 1536) ? bid : bid - 1536) * 256 + tid;
        float4 x = ((const float4*)src)[i];
        us4 v; v.x = f2b(x.x); v.y = f2b(x.y); v.z = f2b(x.z); v.w = f2b(x.w);
        ((us4*)dst)[i] = v;
    } else if (bid < 9984) {
        int t = bid - 7680, w = t / 576, tt = t - w * 576;
        const float* in = (w == 0) ? Wq : (w == 1) ? Wk : (w == 2) ? Wv : Wo;
        ushort_t* out = (w == 0) ? wtq : (w == 1) ? wtk : (w == 2) ? wtv : wto;
        int x = tid & 31, y = tid >> 5;
        int bx = (tt % 24) * 32, by = (tt / 24) * 32;
#pragma unroll
        for (int j = 0; j < 32; j += 8)
            tsh[y + j][x] = f2b(in[(size_t)(by + y + j) * 768 + bx + x]);
        __syncthreads();
#pragma unroll
        for (int j = 0; j < 32; j += 8)
            out[(size_t)(bx + y + j) * 768 + by + x] = tsh[x][y + j];
    } else if (bid < 11520) {
        int idx = (bid - 9984) * 256 + tid;
        int j = idx & 31, q = (idx >> 5) & 1023, h = idx >> 15;
        float pos = q * (31.0f / 1023.0f);
        float fl = floorf(pos);
        int lo = (int)fl; if (lo > 31) lo = 31;
        float w = pos - fl;
        int hi = lo + 1; if (hi > 31) hi = 31;
        float vlo = rel[(h * 32 + lo) * 32 + j];
        float vhi = rel[(h * 32 + hi) * 32 + j];
        b1b[idx] = f2b((vlo + (vhi - vlo) * w) * LOG2E);
    } else {
        int n = (bid - 11520) * 256 + tid;
        float pos = n * (31.0f / 4095.0f);
        float fl = floorf(pos);
        int ln = (int)fl; if (ln > 31) ln = 31;
        float wn = pos - fl;
        int hn = ln + 1; if (hn > 31) hn = 31;
        float vals[32];
#pragma unroll
        for (int j = 0; j < 32; ++j) vals[j] = 0.f;
        vals[ln] += 1.0f - wn;
        vals[hn] += wn;
#pragma unroll
        for (int j = 0; j < 32; ++j) wtab[n * 32 + j] = f2b(vals[j]);
    }
}

// ------------------------------------------------- epilogue store (shared)
__device__ __forceinline__ void gemm_store(float bvf, f32x4 a, void* out,
                                           int mode, int lsh, float scale,
                                           int mbase, int n) {
    if (mode == 0) {
#pragma unroll
        for (int r = 0; r < 4; ++r)
            ((float*)out)[(size_t)(mbase + r) * 768 + n] = (a[r] + bvf) * scale;
    } else if (mode == 1) {
        int h = n >> 6, d = n & 63;
#pragma unroll
        for (int r = 0; r < 4; ++r) {
            int m = mbase + r;
            int b = m >> lsh, l = m & ((1 << lsh) - 1);
            ((ushort_t*)out)[((size_t)(((b * 12 + h) << lsh) + l) << 6) + d] = f2b((a[r] + bvf) * scale);
        }
    } else {
        int h = n >> 6, d = n & 63;
        int b = mbase >> lsh, l = mbase & ((1 << lsh) - 1);
        us4 v;
        v.x = f2b((a[0] + bvf) * scale);
        v.y = f2b((a[1] + bvf) * scale);
        v.z = f2b((a[2] + bvf) * scale);
        v.w = f2b((a[3] + bvf) * scale);
        *(us4*)((ushort_t*)out + ((size_t)((b * 12 + h) * 64 + d) << lsh) + l) = v;
    }
}

// --------------------------------------------- 128x128 GEMM body (m97-style)
__device__ __forceinline__ void gemm_body128(const ushort_t* __restrict__ A,
                                             const ushort_t* __restrict__ Bt,
                                             const float* __restrict__ bias,
                                             void* __restrict__ out,
                                             int mode, int lsh, float scale,
                                             int m0, int n0,
                                             ushort_t* As, ushort_t* Bs, int tid) {
    const int wave = tid >> 6, lane = tid & 63;
    const int quad = lane >> 4, l15 = lane & 15;
    const int wm = wave >> 1, wn = wave & 1;
    const f32x4 z4 = {0.f, 0.f, 0.f, 0.f};
    f32x4 acc[4][4];
#pragma unroll
    for (int i = 0; i < 4; ++i)
#pragma unroll
        for (int j = 0; j < 4; ++j) acc[i][j] = z4;

    const int lrow = lane >> 2;
    const int kswz = ((lane & 3) ^ (lrow & 3)) * 8;

    for (int kk = 0; kk < 768; kk += 32) {
        __syncthreads();
#pragma unroll
        for (int i = 0; i < 2; ++i) {
            int c = wave * 2 + i;
            gld16(A + (size_t)(m0 + c * 16 + lrow) * 768 + kk + kswz, (void*)(As + c * 512));
            gld16(Bt + (size_t)(n0 + c * 16 + lrow) * 768 + kk + kswz, (void*)(Bs + c * 512));
        }
        __syncthreads();
        bf16x8 af[4], bf[4];
#pragma unroll
        for (int mb = 0; mb < 4; ++mb) {
            int r = wm * 64 + mb * 16 + l15;
            af[mb] = *(const bf16x8*)(As + r * 32 + ((quad ^ (r & 3)) * 8));
        }
#pragma unroll
        for (int nb = 0; nb < 4; ++nb) {
            int r = wn * 64 + nb * 16 + l15;
            bf[nb] = *(const bf16x8*)(Bs + r * 32 + ((quad ^ (r & 3)) * 8));
        }
#pragma unroll
        for (int mb = 0; mb < 4; ++mb)
#pragma unroll
            for (int nb = 0; nb < 4; ++nb)
                acc[mb][nb] = __builtin_amdgcn_mfma_f32_16x16x32_bf16(af[mb], bf[nb], acc[mb][nb], 0, 0, 0);
    }

#pragma unroll
    for (int mb = 0; mb < 4; ++mb) {
        int mbase = m0 + wm * 64 + mb * 16 + quad * 4;
#pragma unroll
        for (int nb = 0; nb < 4; ++nb) {
            int n = n0 + wn * 64 + nb * 16 + l15;
            gemm_store(bias[n], acc[mb][nb], out, mode, lsh, scale, mbase, n);
        }
    }
}

// ------------------------------------------- 64x64 GEMM body (for out-proj)
__device__ __forceinline__ void gemm_body64(const ushort_t* __restrict__ A,
                                            const ushort_t* __restrict__ Bt,
                                            const float* __restrict__ bias,
                                            void* __restrict__ out,
                                            int mode, int lsh, float scale,
                                            int m0, int n0,
                                            ushort_t* As, ushort_t* Bs, int tid) {
    const int wave = tid >> 6, lane = tid & 63;
    const int quad = lane >> 4, l15 = lane & 15;
    const f32x4 z4 = {0.f, 0.f, 0.f, 0.f};
    f32x4 acc[4];
#pragma unroll
    for (int j = 0; j < 4; ++j) acc[j] = z4;

    const int lrow = lane >> 2;
    const int kswz = ((lane & 3) ^ (lrow & 3)) * 8;

    for (int kk = 0; kk < 768; kk += 32) {
        __syncthreads();
        gld16(A + (size_t)(m0 + wave * 16 + lrow) * 768 + kk + kswz, (void*)(As + wave * 512));
        gld16(Bt + (size_t)(n0 + wave * 16 + lrow) * 768 + kk + kswz, (void*)(Bs + wave * 512));
        __syncthreads();
        bf16x8 af, bf[4];
        {
            int r = wave * 16 + l15;
            af = *(const bf16x8*)(As + r * 32 + ((quad ^ (r & 3)) * 8));
        }
#pragma unroll
        for (int nb = 0; nb < 4; ++nb) {
            int r = nb * 16 + l15;
            bf[nb] = *(const bf16x8*)(Bs + r * 32 + ((quad ^ (r & 3)) * 8));
        }
#pragma unroll
        for (int nb = 0; nb < 4; ++nb)
            acc[nb] = __builtin_amdgcn_mfma_f32_16x16x32_bf16(af, bf[nb], acc[nb], 0, 0, 0);
    }

    int mbase = m0 + wave * 16 + quad * 4;
#pragma unroll
    for (int nb = 0; nb < 4; ++nb) {
        int n = n0 + nb * 16 + l15;
        gemm_store(bias[n], acc[nb], out, mode, lsh, scale, mbase, n);
    }
}

// ------------------------------------------ fused Q/K/V projections, 128x128
// [0,96): Q   [96,480): K   [480,864): V^T
__global__ __launch_bounds__(256) void proj3(const ushort_t* __restrict__ qc,
                                             const ushort_t* __restrict__ kvc,
                                             const ushort_t* __restrict__ wtq,
                                             const ushort_t* __restrict__ wtk,
                                             const ushort_t* __restrict__ wtv,
                                             const float* __restrict__ bq,
                                             const float* __restrict__ bk,
                                             const float* __restrict__ bv,
                                             ushort_t* __restrict__ qp,
                                             ushort_t* __restrict__ kp,
                                             ushort_t* __restrict__ vtp) {
    __shared__ __align__(16) ushort_t As[128 * 32];
    __shared__ __align__(16) ushort_t Bs[128 * 32];
    const int bid = blockIdx.x, tid = threadIdx.x;
    if (bid < 96) {
        int mt = bid / 6, nt = bid - mt * 6;
        gemm_body128(qc, wtq, bq, qp, 1, 10, QSCALE, mt * 128, nt * 128, As, Bs, tid);
    } else if (bid < 480) {
        int t = bid - 96, mt = t / 6, nt = t - mt * 6;
        gemm_body128(kvc, wtk, bk, kp, 1, 12, 1.0f, mt * 128, nt * 128, As, Bs, tid);
    } else {
        int t = bid - 480, mt = t / 6, nt = t - mt * 6;
        gemm_body128(kvc, wtv, bv, vtp, 2, 12, 1.0f, mt * 128, nt * 128, As, Bs, tid);
    }
}

// ------------------------------------------------------------ output GEMM
__global__ __launch_bounds__(256) void gemm_out(const ushort_t* __restrict__ ab,
                                                const ushort_t* __restrict__ wto,
                                                const float* __restrict__ bo,
                                                float* __restrict__ out) {
    __shared__ __align__(16) ushort_t As[64 * 32];
    __shared__ __align__(16) ushort_t Bs[64 * 32];
    const int bid = blockIdx.x, tid = threadIdx.x;
    int mt = bid / 12, nt = bid - mt * 12;
    gemm_body64(ab, wto, bo, out, 0, 0, 1.0f, mt * 64, nt * 64, As, Bs, tid);
}

// ---------------------------------- flash attention: 128 q-rows, N-split x 4
// Block = (qt, h, b, sp). 4 waves; each wave owns 2 independent 16-row streams
// (rb=0,1) over the shared k/v tile -> intra-wave ILP + shared bk/bv reads.
// Base-2 fixed-max softmax; P goes C-layout -> bf16 LDS (stride 72) ->
// ds_read_b128 A-frags. Unnormalized fp32 O + row sums to ws.
__global__ __launch_bounds__(256) void attn128(const ushort_t* __restrict__ qp,
                                               const ushort_t* __restrict__ kp,
                                               const ushort_t* __restrict__ vt,
                                               const ushort_t* __restrict__ b1b,
                                               const ushort_t* __restrict__ wtab,
                                               float* __restrict__ po,
                                               float* __restrict__ pl) {
    __shared__ __align__(16) ushort_t k_s[64 * 64];
    __shared__ __align__(16) ushort_t v_s[64 * 64];
    __shared__ __align__(16) __bf16 pb[4][2][16 * 72];  // [wave][rb][row*72+col]

    const int tid = threadIdx.x;
    const int wave = tid >> 6, lane = tid & 63;
    const int quad = lane >> 4, l15 = lane & 15;
    const int qt = blockIdx.x, h = blockIdx.y, z = blockIdx.z;
    const int b = z >> 2, sp = z & 3;
    const int q0 = qt * 128;
    const int bh = b * 12 + h;

    const ushort_t* qg = qp + ((size_t)bh * 1024 + q0) * 64;
    const ushort_t* kg = kp + (size_t)bh * 4096 * 64;
    const ushort_t* vg = vt + (size_t)bh * 64 * 4096;

    // per-stream q + bias fragments (registers, loaded once)
    bf16x8 aq[2][2], ab1[2];
#pragma unroll
    for (int rb = 0; rb < 2; ++rb) {
        int rowq = rb * 64 + wave * 16 + l15;
#pragma unroll
        for (int ks = 0; ks < 2; ++ks)
            aq[rb][ks] = *(const bf16x8*)(qg + (size_t)rowq * 64 + (ks * 4 + quad) * 8);
        ab1[rb] = *(const bf16x8*)(b1b + ((size_t)(h * 1024 + q0 + rowq)) * 32 + quad * 8);
    }

    const f32x4 mC = {NEG8L, NEG8L, NEG8L, NEG8L};
    const f32x4 z4 = {0.f, 0.f, 0.f, 0.f};
    f32x4 o[2][4];
    float lsum[2][4];
#pragma unroll
    for (int rb = 0; rb < 2; ++rb) {
#pragma unroll
        for (int d = 0; d < 4; ++d) o[rb][d] = z4;
#pragma unroll
        for (int r = 0; r < 4; ++r) lsum[rb][r] = 0.f;
    }

    const int arow = lane >> 3;
    const int ablk = lane & 7;
    // incremented staging pointers (advance: k +64*64 elems, v +64 elems)
    const int c0 = wave * 2, c1 = wave * 2 + 1;
    const ushort_t* kptr0 = kg + (size_t)(sp * 1024 + c0 * 8 + arow) * 64 + (ablk ^ ((c0 * 8 + arow) & 7)) * 8;
    const ushort_t* kptr1 = kg + (size_t)(sp * 1024 + c1 * 8 + arow) * 64 + (ablk ^ ((c1 * 8 + arow) & 7)) * 8;
    const ushort_t* vptr0 = vg + (size_t)(c0 * 8 + arow) * 4096 + sp * 1024 + (ablk ^ ((c0 * 8 + arow) & 7)) * 8;
    const ushort_t* vptr1 = vg + (size_t)(c1 * 8 + arow) * 4096 + sp * 1024 + (ablk ^ ((c1 * 8 + arow) & 7)) * 8;
    const ushort_t* wptr = wtab + (size_t)(sp * 1024) * 32 + l15 * 32 + quad * 8;

    for (int nt = 0; nt < 16; ++nt) {
        __syncthreads();
        gld16(kptr0, (void*)(k_s + c0 * 512));
        gld16(kptr1, (void*)(k_s + c1 * 512));
        gld16(vptr0, (void*)(v_s + c0 * 512));
        gld16(vptr1, (void*)(v_s + c1 * 512));
        kptr0 += 4096; kptr1 += 4096; vptr0 += 64; vptr1 += 64;
        __syncthreads();

        bf16x8 wf[4];
#pragma unroll
        for (int nb = 0; nb < 4; ++nb)
            wf[nb] = *(const bf16x8*)(wptr + nb * 512);
        wptr += 2048;

        // S for both streams; bk loaded once per (nb,ks)
        f32x4 s0[4], s1[4];
#pragma unroll
        for (int nb = 0; nb < 4; ++nb) {
            s0[nb] = __builtin_amdgcn_mfma_f32_16x16x32_bf16(ab1[0], wf[nb], mC, 0, 0, 0);
            s1[nb] = __builtin_amdgcn_mfma_f32_16x16x32_bf16(ab1[1], wf[nb], mC, 0, 0, 0);
            int rn = nb * 16 + l15;
#pragma unroll
            for (int ks = 0; ks < 2; ++ks) {
                bf16x8 bk = *(const bf16x8*)(k_s + rn * 64 + (((ks * 4 + quad) ^ (rn & 7)) * 8));
                s0[nb] = __builtin_amdgcn_mfma_f32_16x16x32_bf16(aq[0][ks], bk, s0[nb], 0, 0, 0);
                s1[nb] = __builtin_amdgcn_mfma_f32_16x16x32_bf16(aq[1][ks], bk, s1[nb], 0, 0, 0);
            }
        }
        // p = exp2(s); write P into per-stream bf16 LDS (C-layout scatter)
#pragma unroll
        for (int nb = 0; nb < 4; ++nb) {
#pragma unroll
            for (int r = 0; r < 4; ++r) {
                float p0 = exp2f(s0[nb][r]);
                float p1 = exp2f(s1[nb][r]);
                lsum[0][r] += p0;
                lsum[1][r] += p1;
                pb[wave][0][(quad * 4 + r) * 72 + nb * 16 + l15] = (__bf16)p0;
                pb[wave][1][(quad * 4 + r) * 72 + nb * 16 + l15] = (__bf16)p1;
            }
        }
        // PV: A-frags via b128 reads; bv shared across streams
#pragma unroll
        for (int p = 0; p < 2; ++p) {
            bf16x8 ap0 = *(const bf16x8*)&pb[wave][0][l15 * 72 + p * 32 + quad * 8];
            bf16x8 ap1 = *(const bf16x8*)&pb[wave][1][l15 * 72 + p * 32 + quad * 8];
#pragma unroll
            for (int d = 0; d < 4; ++d) {
                int rd = d * 16 + l15;
                bf16x8 bv = *(const bf16x8*)(v_s + rd * 64 + (((p * 4 + quad) ^ (rd & 7)) * 8));
                o[0][d] = __builtin_amdgcn_mfma_f32_16x16x32_bf16(ap0, bv, o[0][d], 0, 0, 0);
                o[1][d] = __builtin_amdgcn_mfma_f32_16x16x32_bf16(ap1, bv, o[1][d], 0, 0, 0);
            }
        }
    }

#pragma unroll
    for (int rb = 0; rb < 2; ++rb)
#pragma unroll
        for (int r = 0; r < 4; ++r)
#pragma unroll
            for (int off = 1; off < 16; off <<= 1)
                lsum[rb][r] += __shfl_xor(lsum[rb][r], off, 64);

    const size_t pbase = ((size_t)(sp * 24 + bh)) * 1024;
#pragma unroll
    for (int rb = 0; rb < 2; ++rb)
#pragma unroll
        for (int r = 0; r < 4; ++r) {
            int qrow = q0 + rb * 64 + wave * 16 + quad * 4 + r;
            if (l15 == 0) pl[pbase + qrow] = lsum[rb][r];
#pragma unroll
            for (int d = 0; d < 4; ++d)
                po[(pbase + qrow) * 64 + d * 16 + l15] = o[rb][d][r];
        }
}

// ----------------------------------------------------------- split combine
__global__ __launch_bounds__(256) void combine(const float* __restrict__ po,
                                               const float* __restrict__ pl,
                                               ushort_t* __restrict__ ab) {
    int idx = blockIdx.x * 256 + threadIdx.x;
    int e = idx * 4;
    int b = e / 786432;
    int rem = e - b * 786432;
    int q = rem / 768;
    int col = rem - q * 768;
    int h = col >> 6, d = col & 63;
    int bh = b * 12 + h;
    float4 acc = {0.f, 0.f, 0.f, 0.f};
    float l = 0.f;
#pragma unroll
    for (int s = 0; s < 4; ++s) {
        size_t base = ((size_t)(s * 24 + bh)) * 1024 + q;
        float4 v = *(const float4*)(po + base * 64 + d);
        acc.x += v.x; acc.y += v.y; acc.z += v.z; acc.w += v.w;
        l += pl[base];
    }
    float inv = 1.0f / l;
    us4 v;
    v.x = f2b(acc.x * inv); v.y = f2b(acc.y * inv);
    v.z = f2b(acc.z * inv); v.w = f2b(acc.w * inv);
    *(us4*)(ab + (size_t)(b * 1024 + q) * 768 + col) = v;
}

// ------------------------------------------------------------------- launch
extern "C" void kernel_launch(void* const* d_in, const int* in_sizes, int n_in,
                              void* d_out, int out_size, void* d_ws, size_t ws_size,
                              hipStream_t stream) {
    const float* query = (const float*)d_in[0];
    const float* keyv  = (const float*)d_in[1];
    const float* Wq = (const float*)d_in[2];
    const float* bq = (const float*)d_in[3];
    const float* Wk = (const float*)d_in[4];
    const float* bk = (const float*)d_in[5];
    const float* Wv = (const float*)d_in[6];
    const float* bv = (const float*)d_in[7];
    const float* Wo = (const float*)d_in[8];
    const float* bo = (const float*)d_in[9];
    const float* rel = (const float*)d_in[10];

    char* ws = (char*)d_ws;
    ushort_t* qc   = (ushort_t*)(ws + 0);
    ushort_t* kvc  = (ushort_t*)(ws + 3145728);
    ushort_t* wtq  = (ushort_t*)(ws + 15728640);
    ushort_t* wtk  = (ushort_t*)(ws + 16908288);
    ushort_t* wtv  = (ushort_t*)(ws + 18087936);
    ushort_t* wto  = (ushort_t*)(ws + 19267584);
    ushort_t* qp   = (ushort_t*)(ws + 20447232);  // [B,H,Q,64] bf16 (x0.125*log2e)
    ushort_t* kp   = (ushort_t*)(ws + 23592960);  // [B,H,N,64] bf16
    ushort_t* vtp  = (ushort_t*)(ws + 36175872);  // [B,H,64,N] bf16
    ushort_t* b1b  = (ushort_t*)(ws + 48758784);  // [H,Q,32] bf16 (x log2e)
    ushort_t* wtab = (ushort_t*)(ws + 49545216);  // [N,32] bf16
    ushort_t* ab   = (ushort_t*)(ws + 49807360);  // [B,Q,768] bf16
    float*    po   = (float*)(ws + 52953088);     // [4,B*H,Q,64] f32
    float*    pl   = (float*)(ws + 78118912);     // [4,B*H,Q] f32
    // total ws usage: 78,512,128 B

    prep<<<11536, 256, 0, stream>>>(query, keyv, Wq, Wk, Wv, Wo, rel,
                                    qc, kvc, wtq, wtk, wtv, wto, b1b, wtab);
    proj3<<<864, 256, 0, stream>>>(qc, kvc, wtq, wtk, wtv, bq, bk, bv, qp, kp, vtp);
    attn128<<<dim3(8, 12, 8), 256, 0, stream>>>(qp, kp, vtp, b1b, wtab, po, pl);
    combine<<<1536, 256, 0, stream>>>(po, pl, ab);
    gemm_out<<<384, 256, 0, stream>>>(ab, wto, bo, (float*)d_out);
}

// Round 6
// 222.240 us; speedup vs baseline: 1.0965x; 1.0965x over previous
//
#include <hip/hip_runtime.h>
#include <stdint.h>

// Problem constants: B=2, Q=1024, N=4096, C=768, H=12, D=64, REL=32
// Inputs/outputs fp32 (established R1/R2).
typedef unsigned short ushort_t;
typedef __bf16 bf16x8 __attribute__((ext_vector_type(8)));
typedef float f32x4 __attribute__((ext_vector_type(4)));
typedef unsigned short us4 __attribute__((ext_vector_type(4)));

#define LOG2E 1.4426950408889634f
#define NEG8L (-11.541560327111707f)   // -8*log2(e)
#define QSCALE 0.18033688011110974f    // 0.125*log2(e)

__device__ __forceinline__ ushort_t f2b(float f) {
    unsigned u = __float_as_uint(f);
    unsigned r = (u + 0x7fffu + ((u >> 16) & 1u)) >> 16;
    return (ushort_t)r;
}
__device__ __forceinline__ void gld16(const void* g, void* l) {
    __builtin_amdgcn_global_load_lds(
        (__attribute__((address_space(1))) void*)g,
        (__attribute__((address_space(3))) void*)l,
        16, 0, 0);
}

// ------------------------------------------------------------ fused prep
// [0,1536): query f32->bf16  [1536,7680): key_value f32->bf16
// [7680,9984): 4x weight transpose  [9984,11520): bias q-lerp (x LOG2E)
// [11520,11536): n-lerp weight table
__global__ __launch_bounds__(256) void prep(
        const float* __restrict__ query, const float* __restrict__ keyv,
        const float* __restrict__ Wq, const float* __restrict__ Wk,
        const float* __restrict__ Wv, const float* __restrict__ Wo,
        const float* __restrict__ rel,
        ushort_t* __restrict__ qc, ushort_t* __restrict__ kvc,
        ushort_t* __restrict__ wtq, ushort_t* __restrict__ wtk,
        ushort_t* __restrict__ wtv, ushort_t* __restrict__ wto,
        ushort_t* __restrict__ b1b, ushort_t* __restrict__ wtab) {
    __shared__ ushort_t tsh[32][33];
    const int bid = blockIdx.x, tid = threadIdx.x;
    if (bid < 7680) {
        const float* src = (bid < 1536) ? query : keyv;
        ushort_t* dst = (bid < 1536) ? qc : kvc;
        int i = ((bid < 1536) ? bid : bid - 1536) * 256 + tid;
        float4 x = ((const float4*)src)[i];
        us4 v; v.x = f2b(x.x); v.y = f2b(x.y); v.z = f2b(x.z); v.w = f2b(x.w);
        ((us4*)dst)[i] = v;
    } else if (bid < 9984) {
        int t = bid - 7680, w = t / 576, tt = t - w * 576;
        const float* in = (w == 0) ? Wq : (w == 1) ? Wk : (w == 2) ? Wv : Wo;
        ushort_t* out = (w == 0) ? wtq : (w == 1) ? wtk : (w == 2) ? wtv : wto;
        int x = tid & 31, y = tid >> 5;
        int bx = (tt % 24) * 32, by = (tt / 24) * 32;
#pragma unroll
        for (int j = 0; j < 32; j += 8)
            tsh[y + j][x] = f2b(in[(size_t)(by + y + j) * 768 + bx + x]);
        __syncthreads();
#pragma unroll
        for (int j = 0; j < 32; j += 8)
            out[(size_t)(bx + y + j) * 768 + by + x] = tsh[x][y + j];
    } else if (bid < 11520) {
        int idx = (bid - 9984) * 256 + tid;
        int j = idx & 31, q = (idx >> 5) & 1023, h = idx >> 15;
        float pos = q * (31.0f / 1023.0f);
        float fl = floorf(pos);
        int lo = (int)fl; if (lo > 31) lo = 31;
        float w = pos - fl;
        int hi = lo + 1; if (hi > 31) hi = 31;
        float vlo = rel[(h * 32 + lo) * 32 + j];
        float vhi = rel[(h * 32 + hi) * 32 + j];
        b1b[idx] = f2b((vlo + (vhi - vlo) * w) * LOG2E);
    } else {
        int n = (bid - 11520) * 256 + tid;
        float pos = n * (31.0f / 4095.0f);
        float fl = floorf(pos);
        int ln = (int)fl; if (ln > 31) ln = 31;
        float wn = pos - fl;
        int hn = ln + 1; if (hn > 31) hn = 31;
        float vals[32];
#pragma unroll
        for (int j = 0; j < 32; ++j) vals[j] = 0.f;
        vals[ln] += 1.0f - wn;
        vals[hn] += wn;
#pragma unroll
        for (int j = 0; j < 32; ++j) wtab[n * 32 + j] = f2b(vals[j]);
    }
}

// ------------------------------------------------- epilogue store (shared)
__device__ __forceinline__ void gemm_store(float bvf, f32x4 a, void* out,
                                           int mode, int lsh, float scale,
                                           int mbase, int n) {
    if (mode == 0) {
#pragma unroll
        for (int r = 0; r < 4; ++r)
            ((float*)out)[(size_t)(mbase + r) * 768 + n] = (a[r] + bvf) * scale;
    } else if (mode == 1) {
        int h = n >> 6, d = n & 63;
#pragma unroll
        for (int r = 0; r < 4; ++r) {
            int m = mbase + r;
            int b = m >> lsh, l = m & ((1 << lsh) - 1);
            ((ushort_t*)out)[((size_t)(((b * 12 + h) << lsh) + l) << 6) + d] = f2b((a[r] + bvf) * scale);
        }
    } else {
        int h = n >> 6, d = n & 63;
        int b = mbase >> lsh, l = mbase & ((1 << lsh) - 1);
        us4 v;
        v.x = f2b((a[0] + bvf) * scale);
        v.y = f2b((a[1] + bvf) * scale);
        v.z = f2b((a[2] + bvf) * scale);
        v.w = f2b((a[3] + bvf) * scale);
        *(us4*)((ushort_t*)out + ((size_t)((b * 12 + h) * 64 + d) << lsh) + l) = v;
    }
}

// --------------------------------------- 128x128 GEMM body, BK=64 (K=768)
// Staging mirrors attn's proven 8-row-chunk XOR pattern: chunk c = 8 rows x
// 64 k; LDS pos blk holds global k-block (blk ^ (row&7)).
__device__ __forceinline__ void gemm_body128(const ushort_t* __restrict__ A,
                                             const ushort_t* __restrict__ Bt,
                                             const float* __restrict__ bias,
                                             void* __restrict__ out,
                                             int mode, int lsh, float scale,
                                             int m0, int n0,
                                             ushort_t* As, ushort_t* Bs, int tid) {
    const int wave = tid >> 6, lane = tid & 63;
    const int quad = lane >> 4, l15 = lane & 15;
    const int wm = wave >> 1, wn = wave & 1;
    const f32x4 z4 = {0.f, 0.f, 0.f, 0.f};
    f32x4 acc[4][4];
#pragma unroll
    for (int i = 0; i < 4; ++i)
#pragma unroll
        for (int j = 0; j < 4; ++j) acc[i][j] = z4;

    const int arow = lane >> 3;        // row within 8-row chunk
    const int ablk = lane & 7;         // 16B block 0..7
    const int kswz = (ablk ^ arow) * 8;

    for (int kk = 0; kk < 768; kk += 64) {
        __syncthreads();
#pragma unroll
        for (int i = 0; i < 4; ++i) {
            int c = wave * 4 + i;      // 16 chunks of 8 rows = 128 rows
            gld16(A + (size_t)(m0 + c * 8 + arow) * 768 + kk + kswz, (void*)(As + c * 512));
            gld16(Bt + (size_t)(n0 + c * 8 + arow) * 768 + kk + kswz, (void*)(Bs + c * 512));
        }
        __syncthreads();
#pragma unroll
        for (int ks = 0; ks < 2; ++ks) {
            bf16x8 af[4], bf[4];
#pragma unroll
            for (int mb = 0; mb < 4; ++mb) {
                int r = wm * 64 + mb * 16 + l15;
                af[mb] = *(const bf16x8*)(As + r * 64 + (((ks * 4 + quad) ^ (r & 7)) * 8));
            }
#pragma unroll
            for (int nb = 0; nb < 4; ++nb) {
                int r = wn * 64 + nb * 16 + l15;
                bf[nb] = *(const bf16x8*)(Bs + r * 64 + (((ks * 4 + quad) ^ (r & 7)) * 8));
            }
#pragma unroll
            for (int mb = 0; mb < 4; ++mb)
#pragma unroll
                for (int nb = 0; nb < 4; ++nb)
                    acc[mb][nb] = __builtin_amdgcn_mfma_f32_16x16x32_bf16(af[mb], bf[nb], acc[mb][nb], 0, 0, 0);
        }
    }

#pragma unroll
    for (int mb = 0; mb < 4; ++mb) {
        int mbase = m0 + wm * 64 + mb * 16 + quad * 4;
#pragma unroll
        for (int nb = 0; nb < 4; ++nb) {
            int n = n0 + wn * 64 + nb * 16 + l15;
            gemm_store(bias[n], acc[mb][nb], out, mode, lsh, scale, mbase, n);
        }
    }
}

// ----------------------------------------- 64x64 GEMM body, BK=64 (out-proj)
__device__ __forceinline__ void gemm_body64(const ushort_t* __restrict__ A,
                                            const ushort_t* __restrict__ Bt,
                                            const float* __restrict__ bias,
                                            void* __restrict__ out,
                                            int mode, int lsh, float scale,
                                            int m0, int n0,
                                            ushort_t* As, ushort_t* Bs, int tid) {
    const int wave = tid >> 6, lane = tid & 63;
    const int quad = lane >> 4, l15 = lane & 15;
    const f32x4 z4 = {0.f, 0.f, 0.f, 0.f};
    f32x4 acc[4];
#pragma unroll
    for (int j = 0; j < 4; ++j) acc[j] = z4;

    const int arow = lane >> 3;
    const int ablk = lane & 7;
    const int kswz = (ablk ^ arow) * 8;

    for (int kk = 0; kk < 768; kk += 64) {
        __syncthreads();
#pragma unroll
        for (int i = 0; i < 2; ++i) {
            int c = wave * 2 + i;      // 8 chunks of 8 rows = 64 rows
            gld16(A + (size_t)(m0 + c * 8 + arow) * 768 + kk + kswz, (void*)(As + c * 512));
            gld16(Bt + (size_t)(n0 + c * 8 + arow) * 768 + kk + kswz, (void*)(Bs + c * 512));
        }
        __syncthreads();
#pragma unroll
        for (int ks = 0; ks < 2; ++ks) {
            bf16x8 af, bf[4];
            {
                int r = wave * 16 + l15;
                af = *(const bf16x8*)(As + r * 64 + (((ks * 4 + quad) ^ (r & 7)) * 8));
            }
#pragma unroll
            for (int nb = 0; nb < 4; ++nb) {
                int r = nb * 16 + l15;
                bf[nb] = *(const bf16x8*)(Bs + r * 64 + (((ks * 4 + quad) ^ (r & 7)) * 8));
            }
#pragma unroll
            for (int nb = 0; nb < 4; ++nb)
                acc[nb] = __builtin_amdgcn_mfma_f32_16x16x32_bf16(af, bf[nb], acc[nb], 0, 0, 0);
        }
    }

    int mbase = m0 + wave * 16 + quad * 4;
#pragma unroll
    for (int nb = 0; nb < 4; ++nb) {
        int n = n0 + nb * 16 + l15;
        gemm_store(bias[n], acc[nb], out, mode, lsh, scale, mbase, n);
    }
}

// ------------------------------------------ fused Q/K/V projections, 128x128
// [0,96): Q   [96,480): K   [480,864): V^T
__global__ __launch_bounds__(256) void proj3(const ushort_t* __restrict__ qc,
                                             const ushort_t* __restrict__ kvc,
                                             const ushort_t* __restrict__ wtq,
                                             const ushort_t* __restrict__ wtk,
                                             const ushort_t* __restrict__ wtv,
                                             const float* __restrict__ bq,
                                             const float* __restrict__ bk,
                                             const float* __restrict__ bv,
                                             ushort_t* __restrict__ qp,
                                             ushort_t* __restrict__ kp,
                                             ushort_t* __restrict__ vtp) {
    __shared__ __align__(16) ushort_t As[128 * 64];
    __shared__ __align__(16) ushort_t Bs[128 * 64];
    const int bid = blockIdx.x, tid = threadIdx.x;
    if (bid < 96) {
        int mt = bid / 6, nt = bid - mt * 6;
        gemm_body128(qc, wtq, bq, qp, 1, 10, QSCALE, mt * 128, nt * 128, As, Bs, tid);
    } else if (bid < 480) {
        int t = bid - 96, mt = t / 6, nt = t - mt * 6;
        gemm_body128(kvc, wtk, bk, kp, 1, 12, 1.0f, mt * 128, nt * 128, As, Bs, tid);
    } else {
        int t = bid - 480, mt = t / 6, nt = t - mt * 6;
        gemm_body128(kvc, wtv, bv, vtp, 2, 12, 1.0f, mt * 128, nt * 128, As, Bs, tid);
    }
}

// ------------------------------------------------------------ output GEMM
__global__ __launch_bounds__(256) void gemm_out(const ushort_t* __restrict__ ab,
                                                const ushort_t* __restrict__ wto,
                                                const float* __restrict__ bo,
                                                float* __restrict__ out) {
    __shared__ __align__(16) ushort_t As[64 * 64];
    __shared__ __align__(16) ushort_t Bs[64 * 64];
    const int bid = blockIdx.x, tid = threadIdx.x;
    int mt = bid / 12, nt = bid - mt * 12;
    gemm_body64(ab, wto, bo, out, 0, 0, 1.0f, mt * 64, nt * 64, As, Bs, tid);
}

// --------------------------------------------- flash attention, N-split x 4
// (R4-proven version: 64 q-rows/block, fp32 LDS P-transpose stride 18,
//  0 bank conflicts, Occ 37%.) Base-2 fixed-max softmax; partials to ws.
__global__ __launch_bounds__(256) void attn64s(const ushort_t* __restrict__ qp,
                                               const ushort_t* __restrict__ kp,
                                               const ushort_t* __restrict__ vt,
                                               const ushort_t* __restrict__ b1b,
                                               const ushort_t* __restrict__ wtab,
                                               float* __restrict__ po,
                                               float* __restrict__ pl) {
    __shared__ __align__(16) ushort_t k_s[64 * 64];
    __shared__ __align__(16) ushort_t v_s[64 * 64];
    __shared__ __align__(16) float pf[4][576];   // per-wave 32 cols x stride 18

    const int tid = threadIdx.x;
    const int wave = tid >> 6, lane = tid & 63;
    const int quad = lane >> 4, l15 = lane & 15;
    const int qt = blockIdx.x, h = blockIdx.y, z = blockIdx.z;
    const int b = z >> 2, sp = z & 3;
    const int q0 = qt * 64;
    const int bh = b * 12 + h;

    const ushort_t* qg = qp + ((size_t)bh * 1024 + q0) * 64;
    const ushort_t* kg = kp + (size_t)bh * 4096 * 64;
    const ushort_t* vg = vt + (size_t)bh * 64 * 4096;

    const int rowq = wave * 16 + l15;
    bf16x8 aq[2];
#pragma unroll
    for (int ks = 0; ks < 2; ++ks)
        aq[ks] = *(const bf16x8*)(qg + (size_t)rowq * 64 + (ks * 4 + quad) * 8);
    bf16x8 ab1 = *(const bf16x8*)(b1b + ((size_t)(h * 1024 + q0 + rowq)) * 32 + quad * 8);

    const f32x4 mC = {NEG8L, NEG8L, NEG8L, NEG8L};
    const f32x4 z4 = {0.f, 0.f, 0.f, 0.f};
    f32x4 o[4];
    float lsum[4];
#pragma unroll
    for (int d = 0; d < 4; ++d) o[d] = z4;
#pragma unroll
    for (int r = 0; r < 4; ++r) lsum[r] = 0.f;

    const int arow = lane >> 3;
    const int ablk = lane & 7;

    for (int nt = 0; nt < 16; ++nt) {
        const int n0 = sp * 1024 + nt * 64;
        __syncthreads();
#pragma unroll
        for (int i = 0; i < 2; ++i) {
            int c = wave * 2 + i;
            int row = c * 8 + arow;
            int k16 = ablk ^ (row & 7);
            gld16(kg + (size_t)(n0 + row) * 64 + k16 * 8, (void*)(k_s + c * 512));
            gld16(vg + (size_t)row * 4096 + n0 + k16 * 8, (void*)(v_s + c * 512));
        }
        __syncthreads();

        bf16x8 wf[4];
#pragma unroll
        for (int nb = 0; nb < 4; ++nb)
            wf[nb] = *(const bf16x8*)(wtab + (size_t)(n0 + nb * 16 + l15) * 32 + quad * 8);

        // s = log2e*(qk*0.125 + bias) - 8*log2e
        f32x4 s[4];
#pragma unroll
        for (int nb = 0; nb < 4; ++nb) {
            s[nb] = __builtin_amdgcn_mfma_f32_16x16x32_bf16(ab1, wf[nb], mC, 0, 0, 0);
#pragma unroll
            for (int ks = 0; ks < 2; ++ks) {
                int rn = nb * 16 + l15;
                bf16x8 bk = *(const bf16x8*)(k_s + rn * 64 + (((ks * 4 + quad) ^ (rn & 7)) * 8));
                s[nb] = __builtin_amdgcn_mfma_f32_16x16x32_bf16(aq[ks], bk, s[nb], 0, 0, 0);
            }
        }
#pragma unroll
        for (int nb = 0; nb < 4; ++nb)
#pragma unroll
            for (int r = 0; r < 4; ++r) {
                float p = exp2f(s[nb][r]);
                s[nb][r] = p;
                lsum[r] += p;
            }
        // P transpose: C-layout fp32 -> wave-private LDS (stride 18) -> A-layout
#pragma unroll
        for (int p = 0; p < 2; ++p) {
#pragma unroll
            for (int i = 0; i < 2; ++i) {
                int nb = 2 * p + i;
                float* dst = &pf[wave][(i * 16 + l15) * 18 + quad * 4];
                *(float2*)dst = make_float2(s[nb][0], s[nb][1]);
                *(float2*)(dst + 2) = make_float2(s[nb][2], s[nb][3]);
            }
            bf16x8 ap;
#pragma unroll
            for (int j = 0; j < 8; ++j)
                ap[j] = (__bf16)pf[wave][(quad * 8 + j) * 18 + l15];
#pragma unroll
            for (int d = 0; d < 4; ++d) {
                int rd = d * 16 + l15;
                bf16x8 bv = *(const bf16x8*)(v_s + rd * 64 + (((p * 4 + quad) ^ (rd & 7)) * 8));
                o[d] = __builtin_amdgcn_mfma_f32_16x16x32_bf16(ap, bv, o[d], 0, 0, 0);
            }
        }
    }

#pragma unroll
    for (int r = 0; r < 4; ++r)
#pragma unroll
        for (int off = 1; off < 16; off <<= 1)
            lsum[r] += __shfl_xor(lsum[r], off, 64);

    const size_t pbase = ((size_t)(sp * 24 + bh)) * 1024;
#pragma unroll
    for (int r = 0; r < 4; ++r) {
        int qrow = q0 + wave * 16 + quad * 4 + r;
        if (l15 == 0) pl[pbase + qrow] = lsum[r];
#pragma unroll
        for (int d = 0; d < 4; ++d)
            po[(pbase + qrow) * 64 + d * 16 + l15] = o[d][r];
    }
}

// ----------------------------------------------------------- split combine
__global__ __launch_bounds__(256) void combine(const float* __restrict__ po,
                                               const float* __restrict__ pl,
                                               ushort_t* __restrict__ ab) {
    int idx = blockIdx.x * 256 + threadIdx.x;
    int e = idx * 4;
    int b = e / 786432;
    int rem = e - b * 786432;
    int q = rem / 768;
    int col = rem - q * 768;
    int h = col >> 6, d = col & 63;
    int bh = b * 12 + h;
    float4 acc = {0.f, 0.f, 0.f, 0.f};
    float l = 0.f;
#pragma unroll
    for (int s = 0; s < 4; ++s) {
        size_t base = ((size_t)(s * 24 + bh)) * 1024 + q;
        float4 v = *(const float4*)(po + base * 64 + d);
        acc.x += v.x; acc.y += v.y; acc.z += v.z; acc.w += v.w;
        l += pl[base];
    }
    float inv = 1.0f / l;
    us4 v;
    v.x = f2b(acc.x * inv); v.y = f2b(acc.y * inv);
    v.z = f2b(acc.z * inv); v.w = f2b(acc.w * inv);
    *(us4*)(ab + (size_t)(b * 1024 + q) * 768 + col) = v;
}

// ------------------------------------------------------------------- launch
extern "C" void kernel_launch(void* const* d_in, const int* in_sizes, int n_in,
                              void* d_out, int out_size, void* d_ws, size_t ws_size,
                              hipStream_t stream) {
    const float* query = (const float*)d_in[0];
    const float* keyv  = (const float*)d_in[1];
    const float* Wq = (const float*)d_in[2];
    const float* bq = (const float*)d_in[3];
    const float* Wk = (const float*)d_in[4];
    const float* bk = (const float*)d_in[5];
    const float* Wv = (const float*)d_in[6];
    const float* bv = (const float*)d_in[7];
    const float* Wo = (const float*)d_in[8];
    const float* bo = (const float*)d_in[9];
    const float* rel = (const float*)d_in[10];

    char* ws = (char*)d_ws;
    ushort_t* qc   = (ushort_t*)(ws + 0);
    ushort_t* kvc  = (ushort_t*)(ws + 3145728);
    ushort_t* wtq  = (ushort_t*)(ws + 15728640);
    ushort_t* wtk  = (ushort_t*)(ws + 16908288);
    ushort_t* wtv  = (ushort_t*)(ws + 18087936);
    ushort_t* wto  = (ushort_t*)(ws + 19267584);
    ushort_t* qp   = (ushort_t*)(ws + 20447232);  // [B,H,Q,64] bf16 (x0.125*log2e)
    ushort_t* kp   = (ushort_t*)(ws + 23592960);  // [B,H,N,64] bf16
    ushort_t* vtp  = (ushort_t*)(ws + 36175872);  // [B,H,64,N] bf16
    ushort_t* b1b  = (ushort_t*)(ws + 48758784);  // [H,Q,32] bf16 (x log2e)
    ushort_t* wtab = (ushort_t*)(ws + 49545216);  // [N,32] bf16
    ushort_t* ab   = (ushort_t*)(ws + 49807360);  // [B,Q,768] bf16
    float*    po   = (float*)(ws + 52953088);     // [4,B*H,Q,64] f32
    float*    pl   = (float*)(ws + 78118912);     // [4,B*H,Q] f32
    // total ws usage: 78,512,128 B

    prep<<<11536, 256, 0, stream>>>(query, keyv, Wq, Wk, Wv, Wo, rel,
                                    qc, kvc, wtq, wtk, wtv, wto, b1b, wtab);
    proj3<<<864, 256, 0, stream>>>(qc, kvc, wtq, wtk, wtv, bq, bk, bv, qp, kp, vtp);
    attn64s<<<dim3(16, 12, 8), 256, 0, stream>>>(qp, kp, vtp, b1b, wtab, po, pl);
    combine<<<1536, 256, 0, stream>>>(po, pl, ab);
    gemm_out<<<384, 256, 0, stream>>>(ab, wto, bo, (float*)d_out);
}

// Round 7
// 215.687 us; speedup vs baseline: 1.1299x; 1.0304x over previous
//
#include <hip/hip_runtime.h>
#include <stdint.h>

// Problem constants: B=2, Q=1024, N=4096, C=768, H=12, D=64, REL=32
// Inputs/outputs fp32 (established R1/R2).
typedef unsigned short ushort_t;
typedef __bf16 bf16x8 __attribute__((ext_vector_type(8)));
typedef float f32x4 __attribute__((ext_vector_type(4)));
typedef unsigned short us4 __attribute__((ext_vector_type(4)));

#define LOG2E 1.4426950408889634f
#define NEG8L (-11.541560327111707f)   // -8*log2(e)
#define QSCALE 0.18033688011110974f    // 0.125*log2(e)

__device__ __forceinline__ ushort_t f2b(float f) {
    unsigned u = __float_as_uint(f);
    unsigned r = (u + 0x7fffu + ((u >> 16) & 1u)) >> 16;
    return (ushort_t)r;
}
__device__ __forceinline__ void gld16(const void* g, void* l) {
    __builtin_amdgcn_global_load_lds(
        (__attribute__((address_space(1))) void*)g,
        (__attribute__((address_space(3))) void*)l,
        16, 0, 0);
}

// ------------------------------------------------------------ fused prep
// [0,1536): query f32->bf16  [1536,7680): key_value f32->bf16
// [7680,9984): 4x weight transpose  [9984,11520): bias q-lerp (x LOG2E)
// [11520,11536): n-lerp weight table
__global__ __launch_bounds__(256) void prep(
        const float* __restrict__ query, const float* __restrict__ keyv,
        const float* __restrict__ Wq, const float* __restrict__ Wk,
        const float* __restrict__ Wv, const float* __restrict__ Wo,
        const float* __restrict__ rel,
        ushort_t* __restrict__ qc, ushort_t* __restrict__ kvc,
        ushort_t* __restrict__ wtq, ushort_t* __restrict__ wtk,
        ushort_t* __restrict__ wtv, ushort_t* __restrict__ wto,
        ushort_t* __restrict__ b1b, ushort_t* __restrict__ wtab) {
    __shared__ ushort_t tsh[32][33];
    const int bid = blockIdx.x, tid = threadIdx.x;
    if (bid < 7680) {
        const float* src = (bid < 1536) ? query : keyv;
        ushort_t* dst = (bid < 1536) ? qc : kvc;
        int i = ((bid < 1536) ? bid : bid - 1536) * 256 + tid;
        float4 x = ((const float4*)src)[i];
        us4 v; v.x = f2b(x.x); v.y = f2b(x.y); v.z = f2b(x.z); v.w = f2b(x.w);
        ((us4*)dst)[i] = v;
    } else if (bid < 9984) {
        int t = bid - 7680, w = t / 576, tt = t - w * 576;
        const float* in = (w == 0) ? Wq : (w == 1) ? Wk : (w == 2) ? Wv : Wo;
        ushort_t* out = (w == 0) ? wtq : (w == 1) ? wtk : (w == 2) ? wtv : wto;
        int x = tid & 31, y = tid >> 5;
        int bx = (tt % 24) * 32, by = (tt / 24) * 32;
#pragma unroll
        for (int j = 0; j < 32; j += 8)
            tsh[y + j][x] = f2b(in[(size_t)(by + y + j) * 768 + bx + x]);
        __syncthreads();
#pragma unroll
        for (int j = 0; j < 32; j += 8)
            out[(size_t)(bx + y + j) * 768 + by + x] = tsh[x][y + j];
    } else if (bid < 11520) {
        int idx = (bid - 9984) * 256 + tid;
        int j = idx & 31, q = (idx >> 5) & 1023, h = idx >> 15;
        float pos = q * (31.0f / 1023.0f);
        float fl = floorf(pos);
        int lo = (int)fl; if (lo > 31) lo = 31;
        float w = pos - fl;
        int hi = lo + 1; if (hi > 31) hi = 31;
        float vlo = rel[(h * 32 + lo) * 32 + j];
        float vhi = rel[(h * 32 + hi) * 32 + j];
        b1b[idx] = f2b((vlo + (vhi - vlo) * w) * LOG2E);
    } else {
        int n = (bid - 11520) * 256 + tid;
        float pos = n * (31.0f / 4095.0f);
        float fl = floorf(pos);
        int ln = (int)fl; if (ln > 31) ln = 31;
        float wn = pos - fl;
        int hn = ln + 1; if (hn > 31) hn = 31;
        float vals[32];
#pragma unroll
        for (int j = 0; j < 32; ++j) vals[j] = 0.f;
        vals[ln] += 1.0f - wn;
        vals[hn] += wn;
#pragma unroll
        for (int j = 0; j < 32; ++j) wtab[n * 32 + j] = f2b(vals[j]);
    }
}

// ------------------------------------------------- epilogue store (shared)
__device__ __forceinline__ void gemm_store(float bvf, f32x4 a, void* out,
                                           int mode, int lsh, float scale,
                                           int mbase, int n) {
    if (mode == 0) {
#pragma unroll
        for (int r = 0; r < 4; ++r)
            ((float*)out)[(size_t)(mbase + r) * 768 + n] = (a[r] + bvf) * scale;
    } else if (mode == 1) {
        int h = n >> 6, d = n & 63;
#pragma unroll
        for (int r = 0; r < 4; ++r) {
            int m = mbase + r;
            int b = m >> lsh, l = m & ((1 << lsh) - 1);
            ((ushort_t*)out)[((size_t)(((b * 12 + h) << lsh) + l) << 6) + d] = f2b((a[r] + bvf) * scale);
        }
    } else {
        int h = n >> 6, d = n & 63;
        int b = mbase >> lsh, l = mbase & ((1 << lsh) - 1);
        us4 v;
        v.x = f2b((a[0] + bvf) * scale);
        v.y = f2b((a[1] + bvf) * scale);
        v.z = f2b((a[2] + bvf) * scale);
        v.w = f2b((a[3] + bvf) * scale);
        *(us4*)((ushort_t*)out + ((size_t)((b * 12 + h) * 64 + d) << lsh) + l) = v;
    }
}

// --------------------------------------- 128x128 GEMM body, BK=64 (K=768)
__device__ __forceinline__ void gemm_body128(const ushort_t* __restrict__ A,
                                             const ushort_t* __restrict__ Bt,
                                             const float* __restrict__ bias,
                                             void* __restrict__ out,
                                             int mode, int lsh, float scale,
                                             int m0, int n0,
                                             ushort_t* As, ushort_t* Bs, int tid) {
    const int wave = tid >> 6, lane = tid & 63;
    const int quad = lane >> 4, l15 = lane & 15;
    const int wm = wave >> 1, wn = wave & 1;
    const f32x4 z4 = {0.f, 0.f, 0.f, 0.f};
    f32x4 acc[4][4];
#pragma unroll
    for (int i = 0; i < 4; ++i)
#pragma unroll
        for (int j = 0; j < 4; ++j) acc[i][j] = z4;

    const int arow = lane >> 3;        // row within 8-row chunk
    const int ablk = lane & 7;         // 16B block 0..7
    const int kswz = (ablk ^ arow) * 8;

    for (int kk = 0; kk < 768; kk += 64) {
        __syncthreads();
#pragma unroll
        for (int i = 0; i < 4; ++i) {
            int c = wave * 4 + i;      // 16 chunks of 8 rows = 128 rows
            gld16(A + (size_t)(m0 + c * 8 + arow) * 768 + kk + kswz, (void*)(As + c * 512));
            gld16(Bt + (size_t)(n0 + c * 8 + arow) * 768 + kk + kswz, (void*)(Bs + c * 512));
        }
        __syncthreads();
#pragma unroll
        for (int ks = 0; ks < 2; ++ks) {
            bf16x8 af[4], bf[4];
#pragma unroll
            for (int mb = 0; mb < 4; ++mb) {
                int r = wm * 64 + mb * 16 + l15;
                af[mb] = *(const bf16x8*)(As + r * 64 + (((ks * 4 + quad) ^ (r & 7)) * 8));
            }
#pragma unroll
            for (int nb = 0; nb < 4; ++nb) {
                int r = wn * 64 + nb * 16 + l15;
                bf[nb] = *(const bf16x8*)(Bs + r * 64 + (((ks * 4 + quad) ^ (r & 7)) * 8));
            }
#pragma unroll
            for (int mb = 0; mb < 4; ++mb)
#pragma unroll
                for (int nb = 0; nb < 4; ++nb)
                    acc[mb][nb] = __builtin_amdgcn_mfma_f32_16x16x32_bf16(af[mb], bf[nb], acc[mb][nb], 0, 0, 0);
        }
    }

#pragma unroll
    for (int mb = 0; mb < 4; ++mb) {
        int mbase = m0 + wm * 64 + mb * 16 + quad * 4;
#pragma unroll
        for (int nb = 0; nb < 4; ++nb) {
            int n = n0 + wn * 64 + nb * 16 + l15;
            gemm_store(bias[n], acc[mb][nb], out, mode, lsh, scale, mbase, n);
        }
    }
}

// ----------------------------------------- 64x64 GEMM body, BK=64 (out-proj)
__device__ __forceinline__ void gemm_body64(const ushort_t* __restrict__ A,
                                            const ushort_t* __restrict__ Bt,
                                            const float* __restrict__ bias,
                                            void* __restrict__ out,
                                            int mode, int lsh, float scale,
                                            int m0, int n0,
                                            ushort_t* As, ushort_t* Bs, int tid) {
    const int wave = tid >> 6, lane = tid & 63;
    const int quad = lane >> 4, l15 = lane & 15;
    const f32x4 z4 = {0.f, 0.f, 0.f, 0.f};
    f32x4 acc[4];
#pragma unroll
    for (int j = 0; j < 4; ++j) acc[j] = z4;

    const int arow = lane >> 3;
    const int ablk = lane & 7;
    const int kswz = (ablk ^ arow) * 8;

    for (int kk = 0; kk < 768; kk += 64) {
        __syncthreads();
#pragma unroll
        for (int i = 0; i < 2; ++i) {
            int c = wave * 2 + i;      // 8 chunks of 8 rows = 64 rows
            gld16(A + (size_t)(m0 + c * 8 + arow) * 768 + kk + kswz, (void*)(As + c * 512));
            gld16(Bt + (size_t)(n0 + c * 8 + arow) * 768 + kk + kswz, (void*)(Bs + c * 512));
        }
        __syncthreads();
#pragma unroll
        for (int ks = 0; ks < 2; ++ks) {
            bf16x8 af, bf[4];
            {
                int r = wave * 16 + l15;
                af = *(const bf16x8*)(As + r * 64 + (((ks * 4 + quad) ^ (r & 7)) * 8));
            }
#pragma unroll
            for (int nb = 0; nb < 4; ++nb) {
                int r = nb * 16 + l15;
                bf[nb] = *(const bf16x8*)(Bs + r * 64 + (((ks * 4 + quad) ^ (r & 7)) * 8));
            }
#pragma unroll
            for (int nb = 0; nb < 4; ++nb)
                acc[nb] = __builtin_amdgcn_mfma_f32_16x16x32_bf16(af, bf[nb], acc[nb], 0, 0, 0);
        }
    }

    int mbase = m0 + wave * 16 + quad * 4;
#pragma unroll
    for (int nb = 0; nb < 4; ++nb) {
        int n = n0 + nb * 16 + l15;
        gemm_store(bias[n], acc[nb], out, mode, lsh, scale, mbase, n);
    }
}

// ------------------------------------------ fused Q/K/V projections, 128x128
// XCD-aware decode: mt = t % Mtiles (Mtiles % 8 == 0) so all n-tiles of an
// A row-block share one XCD's L2 (segment offsets 96/480 are both %8==0,
// so K-GEMM and V-GEMM reuse the same kvc row-block on the same XCD too).
__global__ __launch_bounds__(256) void proj3(const ushort_t* __restrict__ qc,
                                             const ushort_t* __restrict__ kvc,
                                             const ushort_t* __restrict__ wtq,
                                             const ushort_t* __restrict__ wtk,
                                             const ushort_t* __restrict__ wtv,
                                             const float* __restrict__ bq,
                                             const float* __restrict__ bk,
                                             const float* __restrict__ bv,
                                             ushort_t* __restrict__ qp,
                                             ushort_t* __restrict__ kp,
                                             ushort_t* __restrict__ vtp) {
    __shared__ __align__(16) ushort_t As[128 * 64];
    __shared__ __align__(16) ushort_t Bs[128 * 64];
    const int bid = blockIdx.x, tid = threadIdx.x;
    if (bid < 96) {
        int mt = bid & 15, nt = bid >> 4;
        gemm_body128(qc, wtq, bq, qp, 1, 10, QSCALE, mt * 128, nt * 128, As, Bs, tid);
    } else if (bid < 480) {
        int t = bid - 96, mt = t & 63, nt = t >> 6;
        gemm_body128(kvc, wtk, bk, kp, 1, 12, 1.0f, mt * 128, nt * 128, As, Bs, tid);
    } else {
        int t = bid - 480, mt = t & 63, nt = t >> 6;
        gemm_body128(kvc, wtv, bv, vtp, 2, 12, 1.0f, mt * 128, nt * 128, As, Bs, tid);
    }
}

// ------------------------------------------------------------ output GEMM
__global__ __launch_bounds__(256) void gemm_out(const ushort_t* __restrict__ ab,
                                                const ushort_t* __restrict__ wto,
                                                const float* __restrict__ bo,
                                                float* __restrict__ out) {
    __shared__ __align__(16) ushort_t As[64 * 64];
    __shared__ __align__(16) ushort_t Bs[64 * 64];
    const int bid = blockIdx.x, tid = threadIdx.x;
    int mt = bid & 31, nt = bid >> 5;    // 32 mt (%8==0) -> A-rows XCD-pinned
    gemm_body64(ab, wto, bo, out, 0, 0, 1.0f, mt * 64, nt * 64, As, Bs, tid);
}

// --------------------------------------------- flash attention, N-split x 4
// (R4-proven body.) 1D grid 1536 with XCD pinning: xcd = bid&7; each of the
// 24 (b,h) groups (K/V slice ~1 MB) is pinned to one XCD (3 groups/XCD,
// 3 MB < 4 MB L2) -> K/V fetched ~once from HBM instead of ~3.5x.
__global__ __launch_bounds__(256) void attn64s(const ushort_t* __restrict__ qp,
                                               const ushort_t* __restrict__ kp,
                                               const ushort_t* __restrict__ vt,
                                               const ushort_t* __restrict__ b1b,
                                               const ushort_t* __restrict__ wtab,
                                               float* __restrict__ po,
                                               float* __restrict__ pl) {
    __shared__ __align__(16) ushort_t k_s[64 * 64];
    __shared__ __align__(16) ushort_t v_s[64 * 64];
    __shared__ __align__(16) float pf[4][576];   // per-wave 32 cols x stride 18

    const int tid = threadIdx.x;
    const int wave = tid >> 6, lane = tid & 63;
    const int quad = lane >> 4, l15 = lane & 15;
    const int bid = blockIdx.x;
    const int xcd = bid & 7;
    const int slot = bid >> 3;           // 0..191
    const int g = xcd + 8 * (slot >> 6); // (b,h) group 0..23, pinned to xcd
    const int member = slot & 63;        // 0..63
    const int b = g / 12, h = g - b * 12;
    const int qt = member & 15, sp = member >> 4;
    const int q0 = qt * 64;
    const int bh = g;

    const ushort_t* qg = qp + ((size_t)bh * 1024 + q0) * 64;
    const ushort_t* kg = kp + (size_t)bh * 4096 * 64;
    const ushort_t* vg = vt + (size_t)bh * 64 * 4096;

    const int rowq = wave * 16 + l15;
    bf16x8 aq[2];
#pragma unroll
    for (int ks = 0; ks < 2; ++ks)
        aq[ks] = *(const bf16x8*)(qg + (size_t)rowq * 64 + (ks * 4 + quad) * 8);
    bf16x8 ab1 = *(const bf16x8*)(b1b + ((size_t)(h * 1024 + q0 + rowq)) * 32 + quad * 8);

    const f32x4 mC = {NEG8L, NEG8L, NEG8L, NEG8L};
    const f32x4 z4 = {0.f, 0.f, 0.f, 0.f};
    f32x4 o[4];
    float lsum[4];
#pragma unroll
    for (int d = 0; d < 4; ++d) o[d] = z4;
#pragma unroll
    for (int r = 0; r < 4; ++r) lsum[r] = 0.f;

    const int arow = lane >> 3;
    const int ablk = lane & 7;

    for (int nt = 0; nt < 16; ++nt) {
        const int n0 = sp * 1024 + nt * 64;
        __syncthreads();
#pragma unroll
        for (int i = 0; i < 2; ++i) {
            int c = wave * 2 + i;
            int row = c * 8 + arow;
            int k16 = ablk ^ (row & 7);
            gld16(kg + (size_t)(n0 + row) * 64 + k16 * 8, (void*)(k_s + c * 512));
            gld16(vg + (size_t)row * 4096 + n0 + k16 * 8, (void*)(v_s + c * 512));
        }
        __syncthreads();

        bf16x8 wf[4];
#pragma unroll
        for (int nb = 0; nb < 4; ++nb)
            wf[nb] = *(const bf16x8*)(wtab + (size_t)(n0 + nb * 16 + l15) * 32 + quad * 8);

        // s = log2e*(qk*0.125 + bias) - 8*log2e
        f32x4 s[4];
#pragma unroll
        for (int nb = 0; nb < 4; ++nb) {
            s[nb] = __builtin_amdgcn_mfma_f32_16x16x32_bf16(ab1, wf[nb], mC, 0, 0, 0);
#pragma unroll
            for (int ks = 0; ks < 2; ++ks) {
                int rn = nb * 16 + l15;
                bf16x8 bk = *(const bf16x8*)(k_s + rn * 64 + (((ks * 4 + quad) ^ (rn & 7)) * 8));
                s[nb] = __builtin_amdgcn_mfma_f32_16x16x32_bf16(aq[ks], bk, s[nb], 0, 0, 0);
            }
        }
#pragma unroll
        for (int nb = 0; nb < 4; ++nb)
#pragma unroll
            for (int r = 0; r < 4; ++r) {
                float p = exp2f(s[nb][r]);
                s[nb][r] = p;
                lsum[r] += p;
            }
        // P transpose: C-layout fp32 -> wave-private LDS (stride 18) -> A-layout
#pragma unroll
        for (int p = 0; p < 2; ++p) {
#pragma unroll
            for (int i = 0; i < 2; ++i) {
                int nb = 2 * p + i;
                float* dst = &pf[wave][(i * 16 + l15) * 18 + quad * 4];
                *(float2*)dst = make_float2(s[nb][0], s[nb][1]);
                *(float2*)(dst + 2) = make_float2(s[nb][2], s[nb][3]);
            }
            bf16x8 ap;
#pragma unroll
            for (int j = 0; j < 8; ++j)
                ap[j] = (__bf16)pf[wave][(quad * 8 + j) * 18 + l15];
#pragma unroll
            for (int d = 0; d < 4; ++d) {
                int rd = d * 16 + l15;
                bf16x8 bv = *(const bf16x8*)(v_s + rd * 64 + (((p * 4 + quad) ^ (rd & 7)) * 8));
                o[d] = __builtin_amdgcn_mfma_f32_16x16x32_bf16(ap, bv, o[d], 0, 0, 0);
            }
        }
    }

#pragma unroll
    for (int r = 0; r < 4; ++r)
#pragma unroll
        for (int off = 1; off < 16; off <<= 1)
            lsum[r] += __shfl_xor(lsum[r], off, 64);

    const size_t pbase = ((size_t)(sp * 24 + bh)) * 1024;
#pragma unroll
    for (int r = 0; r < 4; ++r) {
        int qrow = q0 + wave * 16 + quad * 4 + r;
        if (l15 == 0) pl[pbase + qrow] = lsum[r];
#pragma unroll
        for (int d = 0; d < 4; ++d)
            po[(pbase + qrow) * 64 + d * 16 + l15] = o[d][r];
    }
}

// ----------------------------------------------------------- split combine
__global__ __launch_bounds__(256) void combine(const float* __restrict__ po,
                                               const float* __restrict__ pl,
                                               ushort_t* __restrict__ ab) {
    int idx = blockIdx.x * 256 + threadIdx.x;
    int e = idx * 4;
    int b = e / 786432;
    int rem = e - b * 786432;
    int q = rem / 768;
    int col = rem - q * 768;
    int h = col >> 6, d = col & 63;
    int bh = b * 12 + h;
    float4 acc = {0.f, 0.f, 0.f, 0.f};
    float l = 0.f;
#pragma unroll
    for (int s = 0; s < 4; ++s) {
        size_t base = ((size_t)(s * 24 + bh)) * 1024 + q;
        float4 v = *(const float4*)(po + base * 64 + d);
        acc.x += v.x; acc.y += v.y; acc.z += v.z; acc.w += v.w;
        l += pl[base];
    }
    float inv = 1.0f / l;
    us4 v;
    v.x = f2b(acc.x * inv); v.y = f2b(acc.y * inv);
    v.z = f2b(acc.z * inv); v.w = f2b(acc.w * inv);
    *(us4*)(ab + (size_t)(b * 1024 + q) * 768 + col) = v;
}

// ------------------------------------------------------------------- launch
extern "C" void kernel_launch(void* const* d_in, const int* in_sizes, int n_in,
                              void* d_out, int out_size, void* d_ws, size_t ws_size,
                              hipStream_t stream) {
    const float* query = (const float*)d_in[0];
    const float* keyv  = (const float*)d_in[1];
    const float* Wq = (const float*)d_in[2];
    const float* bq = (const float*)d_in[3];
    const float* Wk = (const float*)d_in[4];
    const float* bk = (const float*)d_in[5];
    const float* Wv = (const float*)d_in[6];
    const float* bv = (const float*)d_in[7];
    const float* Wo = (const float*)d_in[8];
    const float* bo = (const float*)d_in[9];
    const float* rel = (const float*)d_in[10];

    char* ws = (char*)d_ws;
    ushort_t* qc   = (ushort_t*)(ws + 0);
    ushort_t* kvc  = (ushort_t*)(ws + 3145728);
    ushort_t* wtq  = (ushort_t*)(ws + 15728640);
    ushort_t* wtk  = (ushort_t*)(ws + 16908288);
    ushort_t* wtv  = (ushort_t*)(ws + 18087936);
    ushort_t* wto  = (ushort_t*)(ws + 19267584);
    ushort_t* qp   = (ushort_t*)(ws + 20447232);  // [B,H,Q,64] bf16 (x0.125*log2e)
    ushort_t* kp   = (ushort_t*)(ws + 23592960);  // [B,H,N,64] bf16
    ushort_t* vtp  = (ushort_t*)(ws + 36175872);  // [B,H,64,N] bf16
    ushort_t* b1b  = (ushort_t*)(ws + 48758784);  // [H,Q,32] bf16 (x log2e)
    ushort_t* wtab = (ushort_t*)(ws + 49545216);  // [N,32] bf16
    ushort_t* ab   = (ushort_t*)(ws + 49807360);  // [B,Q,768] bf16
    float*    po   = (float*)(ws + 52953088);     // [4,B*H,Q,64] f32
    float*    pl   = (float*)(ws + 78118912);     // [4,B*H,Q] f32
    // total ws usage: 78,512,128 B

    prep<<<11536, 256, 0, stream>>>(query, keyv, Wq, Wk, Wv, Wo, rel,
                                    qc, kvc, wtq, wtk, wtv, wto, b1b, wtab);
    proj3<<<864, 256, 0, stream>>>(qc, kvc, wtq, wtk, wtv, bq, bk, bv, qp, kp, vtp);
    attn64s<<<1536, 256, 0, stream>>>(qp, kp, vtp, b1b, wtab, po, pl);
    combine<<<1536, 256, 0, stream>>>(po, pl, ab);
    gemm_out<<<384, 256, 0, stream>>>(ab, wto, bo, (float*)d_out);
}